// Round 17
// baseline (127.307 us; speedup 1.0000x reference)
//
#include <hip/hip_runtime.h>
#include <hip/hip_bf16.h>

// Mean-shift: 3 iterations of X <- eta * X @ (K/deg) + (1-eta) * X,
// K = exp(2 * X^T X), D=32, N=9216. Fused attention formulation.
// R18 (final): byte-exact resubmit of R14 (122.7us, session best) to lock
// it in and replicate R14-vs-R17 (126.5) -- their delta is within the
// session's +/-3-4us noise band; R17's last-flag dropped (neutral/worse).
// Session ledger: 137.3 -> 122.7 via (1) in-register P through swapped
// GEMM1 + sigma-permuted cols (killed the P-slab LDS round-trip & WAR,
// -9%), (2) parallel-burst reduce (-3). msattn is invariant to LDS
// traffic (x0.5), occupancy (x1.7), barrier count/drain, setprio, ILP,
// and full dataflow replacement (R15 zero-LDS/zero-barrier == lockstep);
// all pipes <15% busy (R10 PMC). Fusion regresses: R10 per-block device
// fences, R16 cross-phase regalloc spills (VGPR 128 vs ~180 live).
// Symmetry (K = K^T) rejected: turns the 7-way partial reduce into a
// 72-way one; extra partial traffic > halved GEMM1/exp2 work.
// Structure: pack -> 3x [msattn(504 blocks, 8 waves, 128-key chunks,
// global_load_lds staging, den on MFMA pipe) -> reduce(288x512, one
// parallel read burst)].

#define DIM 32
#define RESO 96
#define NPT (RESO * RESO)          // 9216
#define NITER 3
#define ETA 0.5f
#define SCALE 2.88539008f          // BW * log2(e) = 2 * 1.4426950408

#define QB 128                     // queries per block (8 waves x 16)
#define NQB (NPT / QB)             // 72
#define KSEG 7                     // key segments (grid.y) -> 504 blocks
#define NCHUNK128 (NPT / 128)      // 72 chunks of 128 keys

typedef __bf16 bf16_t;
typedef __bf16 v8bf __attribute__((ext_vector_type(8)));
typedef float  v4f  __attribute__((ext_vector_type(4)));

// Async global->LDS, 16B per lane. LDS dest is wave-uniform base (HW adds
// lane*16B); global src is per-lane.
__device__ __forceinline__ void gload_lds16(const bf16_t* g, bf16_t* l) {
    __builtin_amdgcn_global_load_lds(
        (const __attribute__((address_space(1))) void*)g,
        (__attribute__((address_space(3))) void*)l, 16, 0, 0);
}

// Inverse of the 32-key slot permutation sigma(p) = 16*((p>>2)&1) +
// 4*(p>>3) + (p&3) (slot p in a GEMM2 A/B-frag <-> key offset sigma(p) in
// its 32-key block). cols is stored key-permuted so tileB staging stays a
// contiguous 16B/lane. keyinv(sigma(p)) == p; bijection on [0,32).
__device__ __forceinline__ int keyinv(int m) {
    return ((m & 8) << 1) | ((m & 4) << 1) | ((m & 16) >> 2) | (m & 3);
}

// One-time pack of fp32 X (DIM x NPT) into bf16 row-major (NPT x DIM,
// unpermuted) and bf16 col-major (DIM x NPT, key-permuted by sigma^-1);
// also copies X into d_out slice 0. 32x32 LDS transpose tile so all global
// accesses are coalesced. Grid = NPT/32 = 288 blocks x 256 threads.
__global__ __launch_bounds__(256, 4)
void pack_kernel(const float* __restrict__ X,
                 bf16_t* __restrict__ rows,
                 bf16_t* __restrict__ cols,
                 float* __restrict__ out_copy) {
    __shared__ float tt[32][33];
    const int tid = threadIdx.x;
    const int n0  = blockIdx.x * 32;
    const int inv = keyinv(tid & 31);

    // read 32d x 32n (d-major, n contiguous); cols scatter stays in one
    // 64B window per 32-key block.
#pragma unroll
    for (int j = 0; j < 4; ++j) {
        int d = (tid >> 5) + j * 8;
        int n = tid & 31;
        float v = X[(size_t)d * NPT + n0 + n];
        tt[d][n] = v;
        cols[(size_t)d * NPT + n0 + inv] = (bf16_t)v;
        out_copy[(size_t)d * NPT + n0 + n] = v;
    }
    __syncthreads();

    // write rows (n-major, d contiguous): coalesced
#pragma unroll
    for (int j = 0; j < 4; ++j) {
        int n = (tid >> 5) + j * 8;
        int d = tid & 31;
        rows[(size_t)(n0 + n) * DIM + d] = (bf16_t)tt[d][n];
    }
}

// Fused mean-shift partial kernel. Block = 512 thr = 8 waves; wave w owns
// queries [qb*128 + w*16, +16). All waves consume the same 128-key chunk
// (two 64-key halves) from shared LDS tiles (double-buffered,
// global_load_lds staged, ONE barrier per 128-key chunk). Block covers key
// segment ks; writes fp32 num/den partials. P never touches LDS.
__global__ __launch_bounds__(512, 4)
void msattn_kernel(const float* __restrict__ Xcur,
                   const bf16_t* __restrict__ rows,
                   const bf16_t* __restrict__ cols,
                   float* __restrict__ part_num,
                   float* __restrict__ part_den) {
    // tiles[buf]: two 4096-elem halves (h=0/1, 64 keys each). Within half h:
    // [0..2047] = tileA (GEMM1 A = K rows; subtile t at t*512, lane slot
    // lane*8): element = rows[kc+h*64+t*16+l16][dims quad*8..+7].
    // [2048..4095] = tileB (GEMM2 B; frag r=(hh<<1|g) at 2048+r*512):
    // element = cols_perm[dim hh*16+l16][keys kc+h*64+g*32+quad*8..+7]
    // (cols is sigma-permuted so frag register j = V[g*32+sigma(quad*8+j)]).
    // Lane i reads base+i*16B: conflict-free; global_load_lds writes linearly.
    __shared__ __align__(16) bf16_t tiles[2][8192];

    const int tid  = threadIdx.x;
    const int w    = tid >> 6;
    const int lane = tid & 63;
    const int quad = lane >> 4;
    const int l16  = lane & 15;
    const int qb   = blockIdx.x;
    const int ks   = blockIdx.y;
    const int c0   = (NCHUNK128 * ks) / KSEG;
    const int c1   = (NCHUNK128 * (ks + 1)) / KSEG;
    const int q0w  = qb * QB + w * 16;

    // Q-frag (GEMM1 B operand): B[k=dim quad*8+j][n=query l16], scale folded.
    v8bf qfrag;
#pragma unroll
    for (int j = 0; j < 8; ++j) {
        float v = Xcur[(quad * 8 + j) * NPT + q0w + l16];
        qfrag[j] = (bf16_t)(v * SCALE);
    }

    v8bf ones;
#pragma unroll
    for (int j = 0; j < 8; ++j) ones[j] = (bf16_t)1.0f;

    // Per-wave staging: wave w stages one 1KB piece per 64-key half (2
    // gload_lds dwordx4 per 128-key chunk). dest = buf[h*4096+dstoff+lane*8].
    const bf16_t* gsrc;
    int gdelta, hdelta, dstoff;
    if (w < 4) {           // tileA subtile t=w: rows[kc+t*16+l16][quad*8..]
        gsrc = rows + ((size_t)c0 * 128 + w * 16 + l16) * DIM + quad * 8;
        gdelta = 128 * DIM;
        hdelta = 64 * DIM;
        dstoff = w * 512;
    } else {               // tileB frag r=w-4=(hh<<1|g)
        int r = w - 4, hh = r >> 1, g = r & 1;
        gsrc = cols + (size_t)(hh * 16 + l16) * NPT + c0 * 128 + g * 32 + quad * 8;
        gdelta = 128;
        hdelta = 64;
        dstoff = 2048 + (w - 4) * 512;
    }

    v4f acc0 = {0.f, 0.f, 0.f, 0.f};   // O, dims 0..15  (row=query quad*4+r)
    v4f acc1 = {0.f, 0.f, 0.f, 0.f};   // O, dims 16..31
    v4f dden = {0.f, 0.f, 0.f, 0.f};   // den (all 16 cols equal)

    // Prologue: stage first chunk (both halves) into buffer 0.
    gload_lds16(gsrc,          &tiles[0][dstoff]);
    gload_lds16(gsrc + hdelta, &tiles[0][4096 + dstoff]);
    gsrc += gdelta;
    __syncthreads();

    for (int c = c0; c < c1; ++c) {
        const int cc = c - c0;
        const bf16_t* tb = tiles[cc & 1];

        // Issue next chunk's staging loads first; they stay in flight across
        // this chunk's compute and are drained by the end-of-chunk barrier.
        if (c + 1 < c1) {
            bf16_t* nt = tiles[(cc + 1) & 1];
            gload_lds16(gsrc,          &nt[dstoff]);
            gload_lds16(gsrc + hdelta, &nt[4096 + dstoff]);
            gsrc += gdelta;
        }

#pragma unroll
        for (int h = 0; h < 2; ++h) {
            const bf16_t* th = tb + h * 4096;

            // --- GEMM1 (swapped): s[t] = K-subtile(t) x Q ->
            // D[m=key t*16+quad*4+r][n=query l16]. ---
            v4f s[4];
#pragma unroll
            for (int t = 0; t < 4; ++t) {
                v8bf ka = *(const v8bf*)&th[t * 512 + lane * 8];
                s[t] = __builtin_amdgcn_mfma_f32_16x16x32_bf16(ka, qfrag,
                           (v4f){0.f, 0.f, 0.f, 0.f}, 0, 0, 0);
            }

            // B-frags (independent of GEMM1 -> loads overlap the mfmas).
            v8bf b00 = *(const v8bf*)&th[2048 + 0 * 512 + lane * 8];  // d0..15,  g0
            v8bf b01 = *(const v8bf*)&th[2048 + 1 * 512 + lane * 8];  // d0..15,  g1
            v8bf b10 = *(const v8bf*)&th[2048 + 2 * 512 + lane * 8];  // d16..31, g0
            v8bf b11 = *(const v8bf*)&th[2048 + 3 * 512 + lane * 8];  // d16..31, g1

            // --- exp2 + pack in-register: pa0 = keys of subtiles t=0,1
            // (block g=0), pa1 = t=2,3 (g=1). Register j <-> slot quad*8+j
            // <-> key g*32 + sigma(quad*8+j) = t*16+quad*4+(j&3). ---
            v8bf pa0, pa1;
#pragma unroll
            for (int t = 0; t < 2; ++t)
#pragma unroll
                for (int r = 0; r < 4; ++r)
                    pa0[t * 4 + r] = (bf16_t)__builtin_amdgcn_exp2f(s[t][r]);
#pragma unroll
            for (int t = 0; t < 2; ++t)
#pragma unroll
                for (int r = 0; r < 4; ++r)
                    pa1[t * 4 + r] = (bf16_t)__builtin_amdgcn_exp2f(s[2 + t][r]);

            // --- GEMM2: O[q][d] += P V; den rides the MFMA pipe. ---
            acc0 = __builtin_amdgcn_mfma_f32_16x16x32_bf16(pa0, b00, acc0, 0, 0, 0);
            acc1 = __builtin_amdgcn_mfma_f32_16x16x32_bf16(pa0, b10, acc1, 0, 0, 0);
            dden = __builtin_amdgcn_mfma_f32_16x16x32_bf16(pa0, ones, dden, 0, 0, 0);
            acc0 = __builtin_amdgcn_mfma_f32_16x16x32_bf16(pa1, b01, acc0, 0, 0, 0);
            acc1 = __builtin_amdgcn_mfma_f32_16x16x32_bf16(pa1, b11, acc1, 0, 0, 0);
            dden = __builtin_amdgcn_mfma_f32_16x16x32_bf16(pa1, ones, dden, 0, 0, 0);
        }

        __syncthreads();
    }

    // --- epilogue: each wave owns its 16 queries outright; den comes straight
    // out of the MFMA accumulator (all 16 cols equal). ---
    float* pn = part_num + (size_t)ks * NPT * DIM;
#pragma unroll
    for (int r = 0; r < 4; ++r) {
        int gq = q0w + quad * 4 + r;
        pn[(size_t)gq * DIM + l16]      = acc0[r];
        pn[(size_t)gq * DIM + 16 + l16] = acc1[r];
    }
    if (l16 == 0) {
#pragma unroll
        for (int r = 0; r < 4; ++r)
            part_den[ks * NPT + q0w + quad * 4 + r] = dden[r];
    }
}

// Reduce KSEG partials, apply eta-step, write Xnext + next iteration's bf16
// rows (unpermuted) / cols (sigma^-1 key-permuted). 512 threads; ALL global
// reads issue in one burst (pass-1 split over 2 segment-halves x 256 slots;
// den fully parallel over 224 (ss,q) pairs), then LDS combine + coalesced
// writes. Grid = NPT/32 = 288 blocks.
__global__ __launch_bounds__(512, 2)
void reduce_kernel(const float* __restrict__ part_num,
                   const float* __restrict__ part_den,
                   const float* __restrict__ Xcur,
                   float* __restrict__ Xnext,
                   bf16_t* __restrict__ rows_out,
                   bf16_t* __restrict__ cols_out) {
    __shared__ float tp[2][32][33];   // per-half num sums (33 stride: no conflicts)
    __shared__ float dpart[KSEG][32]; // per-segment den
    __shared__ float txn[32][33];

    const int tid = threadIdx.x;
    const int q0  = blockIdx.x * 32;
    const int inv = keyinv(tid & 31);

    // Phase A: one parallel global-read burst.
    {
        int slot = tid & 255;          // (qq, dq)
        int sh   = tid >> 8;           // segment half: 0 -> ss 0..3, 1 -> ss 4..6
        int qq = slot >> 3, dq = slot & 7;
        const float* pb = &part_num[(size_t)(q0 + qq) * DIM + dq * 4];
        size_t seg = (size_t)NPT * DIM;
        int ssb = sh * 4;
        v4f s = *(const v4f*)&pb[(ssb + 0) * seg]
              + *(const v4f*)&pb[(ssb + 1) * seg]
              + *(const v4f*)&pb[(ssb + 2) * seg];
        if (sh == 0) s += *(const v4f*)&pb[3 * seg];
#pragma unroll
        for (int k = 0; k < 4; ++k) tp[sh][qq][dq * 4 + k] = s[k];
    }
    if (tid < KSEG * 32) {
        int ss = tid >> 5, q = tid & 31;
        dpart[ss][q] = part_den[ss * NPT + q0 + q];
    }
    __syncthreads();

    // Phase B (d-major: Xcur read, Xnext + cols writes coalesced; cols
    // scatter stays in one 64B window per 32-key block).
#pragma unroll
    for (int e = 0; e < 2; ++e) {
        int idx = tid + e * 512;
        int d = idx >> 5, qq = idx & 31;
        float num = tp[0][qq][d] + tp[1][qq][d];
        float dn = dpart[0][qq] + dpart[1][qq] + dpart[2][qq] + dpart[3][qq]
                 + dpart[4][qq] + dpart[5][qq] + dpart[6][qq];
        float xo = Xcur[(size_t)d * NPT + q0 + qq];
        float xn = ETA * num / dn + (1.0f - ETA) * xo;
        Xnext[(size_t)d * NPT + q0 + qq] = xn;
        cols_out[(size_t)d * NPT + q0 + inv] = (bf16_t)xn;
        txn[qq][d] = xn;
    }
    __syncthreads();

    // Phase C (q-major: rows_out coalesced).
#pragma unroll
    for (int e = 0; e < 2; ++e) {
        int idx = tid + e * 512;
        int qq = idx >> 5, d = idx & 31;
        rows_out[(size_t)(q0 + qq) * DIM + d] = (bf16_t)txn[qq][d];
    }
}

extern "C" void kernel_launch(void* const* d_in, const int* in_sizes, int n_in,
                              void* d_out, int out_size, void* d_ws, size_t ws_size,
                              hipStream_t stream) {
    const float* x_in = (const float*)d_in[0];
    float* out = (float*)d_out;

    const size_t DN = (size_t)DIM * NPT;
    // Workspace: 4 bf16 pack buffers (ping-pong), fp32 partials.
    bf16_t* rows0 = (bf16_t*)d_ws;
    bf16_t* cols0 = rows0 + DN;
    bf16_t* rows1 = cols0 + DN;
    bf16_t* cols1 = rows1 + DN;
    float* part_num = (float*)(cols1 + DN);                 // KSEG * NPT * DIM f32
    float* part_den = part_num + (size_t)KSEG * NPT * DIM;  // KSEG * NPT f32

    pack_kernel<<<NPT / 32, 256, 0, stream>>>(x_in, rows0, cols0, out);

    for (int it = 0; it < NITER; ++it) {
        const float* Xcur = (it == 0) ? x_in : out + (size_t)it * DN;
        bf16_t* rin  = (it & 1) ? rows1 : rows0;
        bf16_t* cin  = (it & 1) ? cols1 : cols0;
        bf16_t* rout = (it & 1) ? rows0 : rows1;
        bf16_t* cout = (it & 1) ? cols0 : cols1;
        msattn_kernel<<<dim3(NQB, KSEG), 512, 0, stream>>>(Xcur, rin, cin,
                                                           part_num, part_den);
        reduce_kernel<<<NPT / 32, 512, 0, stream>>>(part_num, part_den, Xcur,
                                                    out + (size_t)(it + 1) * DN,
                                                    rout, cout);
    }
}

// Round 18
// 123.401 us; speedup vs baseline: 1.0317x; 1.0317x over previous
//
#include <hip/hip_runtime.h>
#include <hip/hip_bf16.h>

// Mean-shift: 3 iterations of X <- eta * X @ (K/deg) + (1-eta) * X,
// K = exp(2 * X^T X), D=32, N=9216. Fused attention formulation.
// R19 (final, plateau-locked): R18's byte-exact R14 replicate returned
// 127.3 vs R14's 122.7 -> the structure's true cost is ~125 +/- 2.5us;
// all recent deltas were noise. Session: 137.3 -> ~122.7 via (1)
// in-register P through swapped GEMM1 + sigma-permuted cols (-9%),
// (2) parallel-burst reduce (-3). msattn (~34us/iter) is invariant to
// LDS traffic (x0.5), occupancy (x1.7), barrier count/drain, setprio,
// ILP, and full dataflow replacement (R15 zero-LDS/zero-barrier ==
// lockstep), with all pipes <15% busy (R10 PMC) and a ~2x gap over the
// per-pipe serial sum -- an exposed-latency / launch-structure cost with
// no remaining HIP-source lever. Fusion regresses by mechanism: R10
// per-block device fences (~1000/dispatch), R16 cross-phase regalloc
// (VGPR 128 vs ~180 live -> spills). Grid-uniformity variants (KSEG
// 6/8/9, QB 144/192/256) all worsen the CU-level tail. Symmetry (K=K^T)
// rejected: 7-way partial reduce becomes 72-way.
// Structure: pack -> 3x [msattn(504 blocks, 8 waves, 128-key chunks,
// global_load_lds staging, den on MFMA pipe) -> reduce(288x512, one
// parallel read burst)].

#define DIM 32
#define RESO 96
#define NPT (RESO * RESO)          // 9216
#define NITER 3
#define ETA 0.5f
#define SCALE 2.88539008f          // BW * log2(e) = 2 * 1.4426950408

#define QB 128                     // queries per block (8 waves x 16)
#define NQB (NPT / QB)             // 72
#define KSEG 7                     // key segments (grid.y) -> 504 blocks
#define NCHUNK128 (NPT / 128)      // 72 chunks of 128 keys

typedef __bf16 bf16_t;
typedef __bf16 v8bf __attribute__((ext_vector_type(8)));
typedef float  v4f  __attribute__((ext_vector_type(4)));

// Async global->LDS, 16B per lane. LDS dest is wave-uniform base (HW adds
// lane*16B); global src is per-lane.
__device__ __forceinline__ void gload_lds16(const bf16_t* g, bf16_t* l) {
    __builtin_amdgcn_global_load_lds(
        (const __attribute__((address_space(1))) void*)g,
        (__attribute__((address_space(3))) void*)l, 16, 0, 0);
}

// Inverse of the 32-key slot permutation sigma(p) = 16*((p>>2)&1) +
// 4*(p>>3) + (p&3) (slot p in a GEMM2 A/B-frag <-> key offset sigma(p) in
// its 32-key block). cols is stored key-permuted so tileB staging stays a
// contiguous 16B/lane. keyinv(sigma(p)) == p; bijection on [0,32).
__device__ __forceinline__ int keyinv(int m) {
    return ((m & 8) << 1) | ((m & 4) << 1) | ((m & 16) >> 2) | (m & 3);
}

// One-time pack of fp32 X (DIM x NPT) into bf16 row-major (NPT x DIM,
// unpermuted) and bf16 col-major (DIM x NPT, key-permuted by sigma^-1);
// also copies X into d_out slice 0. 32x32 LDS transpose tile so all global
// accesses are coalesced. Grid = NPT/32 = 288 blocks x 256 threads.
__global__ __launch_bounds__(256, 4)
void pack_kernel(const float* __restrict__ X,
                 bf16_t* __restrict__ rows,
                 bf16_t* __restrict__ cols,
                 float* __restrict__ out_copy) {
    __shared__ float tt[32][33];
    const int tid = threadIdx.x;
    const int n0  = blockIdx.x * 32;
    const int inv = keyinv(tid & 31);

    // read 32d x 32n (d-major, n contiguous); cols scatter stays in one
    // 64B window per 32-key block.
#pragma unroll
    for (int j = 0; j < 4; ++j) {
        int d = (tid >> 5) + j * 8;
        int n = tid & 31;
        float v = X[(size_t)d * NPT + n0 + n];
        tt[d][n] = v;
        cols[(size_t)d * NPT + n0 + inv] = (bf16_t)v;
        out_copy[(size_t)d * NPT + n0 + n] = v;
    }
    __syncthreads();

    // write rows (n-major, d contiguous): coalesced
#pragma unroll
    for (int j = 0; j < 4; ++j) {
        int n = (tid >> 5) + j * 8;
        int d = tid & 31;
        rows[(size_t)(n0 + n) * DIM + d] = (bf16_t)tt[d][n];
    }
}

// Fused mean-shift partial kernel. Block = 512 thr = 8 waves; wave w owns
// queries [qb*128 + w*16, +16). All waves consume the same 128-key chunk
// (two 64-key halves) from shared LDS tiles (double-buffered,
// global_load_lds staged, ONE barrier per 128-key chunk). Block covers key
// segment ks; writes fp32 num/den partials. P never touches LDS.
__global__ __launch_bounds__(512, 4)
void msattn_kernel(const float* __restrict__ Xcur,
                   const bf16_t* __restrict__ rows,
                   const bf16_t* __restrict__ cols,
                   float* __restrict__ part_num,
                   float* __restrict__ part_den) {
    // tiles[buf]: two 4096-elem halves (h=0/1, 64 keys each). Within half h:
    // [0..2047] = tileA (GEMM1 A = K rows; subtile t at t*512, lane slot
    // lane*8): element = rows[kc+h*64+t*16+l16][dims quad*8..+7].
    // [2048..4095] = tileB (GEMM2 B; frag r=(hh<<1|g) at 2048+r*512):
    // element = cols_perm[dim hh*16+l16][keys kc+h*64+g*32+quad*8..+7]
    // (cols is sigma-permuted so frag register j = V[g*32+sigma(quad*8+j)]).
    // Lane i reads base+i*16B: conflict-free; global_load_lds writes linearly.
    __shared__ __align__(16) bf16_t tiles[2][8192];

    const int tid  = threadIdx.x;
    const int w    = tid >> 6;
    const int lane = tid & 63;
    const int quad = lane >> 4;
    const int l16  = lane & 15;
    const int qb   = blockIdx.x;
    const int ks   = blockIdx.y;
    const int c0   = (NCHUNK128 * ks) / KSEG;
    const int c1   = (NCHUNK128 * (ks + 1)) / KSEG;
    const int q0w  = qb * QB + w * 16;

    // Q-frag (GEMM1 B operand): B[k=dim quad*8+j][n=query l16], scale folded.
    v8bf qfrag;
#pragma unroll
    for (int j = 0; j < 8; ++j) {
        float v = Xcur[(quad * 8 + j) * NPT + q0w + l16];
        qfrag[j] = (bf16_t)(v * SCALE);
    }

    v8bf ones;
#pragma unroll
    for (int j = 0; j < 8; ++j) ones[j] = (bf16_t)1.0f;

    // Per-wave staging: wave w stages one 1KB piece per 64-key half (2
    // gload_lds dwordx4 per 128-key chunk). dest = buf[h*4096+dstoff+lane*8].
    const bf16_t* gsrc;
    int gdelta, hdelta, dstoff;
    if (w < 4) {           // tileA subtile t=w: rows[kc+t*16+l16][quad*8..]
        gsrc = rows + ((size_t)c0 * 128 + w * 16 + l16) * DIM + quad * 8;
        gdelta = 128 * DIM;
        hdelta = 64 * DIM;
        dstoff = w * 512;
    } else {               // tileB frag r=w-4=(hh<<1|g)
        int r = w - 4, hh = r >> 1, g = r & 1;
        gsrc = cols + (size_t)(hh * 16 + l16) * NPT + c0 * 128 + g * 32 + quad * 8;
        gdelta = 128;
        hdelta = 64;
        dstoff = 2048 + (w - 4) * 512;
    }

    v4f acc0 = {0.f, 0.f, 0.f, 0.f};   // O, dims 0..15  (row=query quad*4+r)
    v4f acc1 = {0.f, 0.f, 0.f, 0.f};   // O, dims 16..31
    v4f dden = {0.f, 0.f, 0.f, 0.f};   // den (all 16 cols equal)

    // Prologue: stage first chunk (both halves) into buffer 0.
    gload_lds16(gsrc,          &tiles[0][dstoff]);
    gload_lds16(gsrc + hdelta, &tiles[0][4096 + dstoff]);
    gsrc += gdelta;
    __syncthreads();

    for (int c = c0; c < c1; ++c) {
        const int cc = c - c0;
        const bf16_t* tb = tiles[cc & 1];

        // Issue next chunk's staging loads first; they stay in flight across
        // this chunk's compute and are drained by the end-of-chunk barrier.
        if (c + 1 < c1) {
            bf16_t* nt = tiles[(cc + 1) & 1];
            gload_lds16(gsrc,          &nt[dstoff]);
            gload_lds16(gsrc + hdelta, &nt[4096 + dstoff]);
            gsrc += gdelta;
        }

#pragma unroll
        for (int h = 0; h < 2; ++h) {
            const bf16_t* th = tb + h * 4096;

            // --- GEMM1 (swapped): s[t] = K-subtile(t) x Q ->
            // D[m=key t*16+quad*4+r][n=query l16]. ---
            v4f s[4];
#pragma unroll
            for (int t = 0; t < 4; ++t) {
                v8bf ka = *(const v8bf*)&th[t * 512 + lane * 8];
                s[t] = __builtin_amdgcn_mfma_f32_16x16x32_bf16(ka, qfrag,
                           (v4f){0.f, 0.f, 0.f, 0.f}, 0, 0, 0);
            }

            // B-frags (independent of GEMM1 -> loads overlap the mfmas).
            v8bf b00 = *(const v8bf*)&th[2048 + 0 * 512 + lane * 8];  // d0..15,  g0
            v8bf b01 = *(const v8bf*)&th[2048 + 1 * 512 + lane * 8];  // d0..15,  g1
            v8bf b10 = *(const v8bf*)&th[2048 + 2 * 512 + lane * 8];  // d16..31, g0
            v8bf b11 = *(const v8bf*)&th[2048 + 3 * 512 + lane * 8];  // d16..31, g1

            // --- exp2 + pack in-register: pa0 = keys of subtiles t=0,1
            // (block g=0), pa1 = t=2,3 (g=1). Register j <-> slot quad*8+j
            // <-> key g*32 + sigma(quad*8+j) = t*16+quad*4+(j&3). ---
            v8bf pa0, pa1;
#pragma unroll
            for (int t = 0; t < 2; ++t)
#pragma unroll
                for (int r = 0; r < 4; ++r)
                    pa0[t * 4 + r] = (bf16_t)__builtin_amdgcn_exp2f(s[t][r]);
#pragma unroll
            for (int t = 0; t < 2; ++t)
#pragma unroll
                for (int r = 0; r < 4; ++r)
                    pa1[t * 4 + r] = (bf16_t)__builtin_amdgcn_exp2f(s[2 + t][r]);

            // --- GEMM2: O[q][d] += P V; den rides the MFMA pipe. ---
            acc0 = __builtin_amdgcn_mfma_f32_16x16x32_bf16(pa0, b00, acc0, 0, 0, 0);
            acc1 = __builtin_amdgcn_mfma_f32_16x16x32_bf16(pa0, b10, acc1, 0, 0, 0);
            dden = __builtin_amdgcn_mfma_f32_16x16x32_bf16(pa0, ones, dden, 0, 0, 0);
            acc0 = __builtin_amdgcn_mfma_f32_16x16x32_bf16(pa1, b01, acc0, 0, 0, 0);
            acc1 = __builtin_amdgcn_mfma_f32_16x16x32_bf16(pa1, b11, acc1, 0, 0, 0);
            dden = __builtin_amdgcn_mfma_f32_16x16x32_bf16(pa1, ones, dden, 0, 0, 0);
        }

        __syncthreads();
    }

    // --- epilogue: each wave owns its 16 queries outright; den comes straight
    // out of the MFMA accumulator (all 16 cols equal). ---
    float* pn = part_num + (size_t)ks * NPT * DIM;
#pragma unroll
    for (int r = 0; r < 4; ++r) {
        int gq = q0w + quad * 4 + r;
        pn[(size_t)gq * DIM + l16]      = acc0[r];
        pn[(size_t)gq * DIM + 16 + l16] = acc1[r];
    }
    if (l16 == 0) {
#pragma unroll
        for (int r = 0; r < 4; ++r)
            part_den[ks * NPT + q0w + quad * 4 + r] = dden[r];
    }
}

// Reduce KSEG partials, apply eta-step, write Xnext + next iteration's bf16
// rows (unpermuted) / cols (sigma^-1 key-permuted). 512 threads; ALL global
// reads issue in one burst (pass-1 split over 2 segment-halves x 256 slots;
// den fully parallel over 224 (ss,q) pairs), then LDS combine + coalesced
// writes. Grid = NPT/32 = 288 blocks.
__global__ __launch_bounds__(512, 2)
void reduce_kernel(const float* __restrict__ part_num,
                   const float* __restrict__ part_den,
                   const float* __restrict__ Xcur,
                   float* __restrict__ Xnext,
                   bf16_t* __restrict__ rows_out,
                   bf16_t* __restrict__ cols_out) {
    __shared__ float tp[2][32][33];   // per-half num sums (33 stride: no conflicts)
    __shared__ float dpart[KSEG][32]; // per-segment den
    __shared__ float txn[32][33];

    const int tid = threadIdx.x;
    const int q0  = blockIdx.x * 32;
    const int inv = keyinv(tid & 31);

    // Phase A: one parallel global-read burst.
    {
        int slot = tid & 255;          // (qq, dq)
        int sh   = tid >> 8;           // segment half: 0 -> ss 0..3, 1 -> ss 4..6
        int qq = slot >> 3, dq = slot & 7;
        const float* pb = &part_num[(size_t)(q0 + qq) * DIM + dq * 4];
        size_t seg = (size_t)NPT * DIM;
        int ssb = sh * 4;
        v4f s = *(const v4f*)&pb[(ssb + 0) * seg]
              + *(const v4f*)&pb[(ssb + 1) * seg]
              + *(const v4f*)&pb[(ssb + 2) * seg];
        if (sh == 0) s += *(const v4f*)&pb[3 * seg];
#pragma unroll
        for (int k = 0; k < 4; ++k) tp[sh][qq][dq * 4 + k] = s[k];
    }
    if (tid < KSEG * 32) {
        int ss = tid >> 5, q = tid & 31;
        dpart[ss][q] = part_den[ss * NPT + q0 + q];
    }
    __syncthreads();

    // Phase B (d-major: Xcur read, Xnext + cols writes coalesced; cols
    // scatter stays in one 64B window per 32-key block).
#pragma unroll
    for (int e = 0; e < 2; ++e) {
        int idx = tid + e * 512;
        int d = idx >> 5, qq = idx & 31;
        float num = tp[0][qq][d] + tp[1][qq][d];
        float dn = dpart[0][qq] + dpart[1][qq] + dpart[2][qq] + dpart[3][qq]
                 + dpart[4][qq] + dpart[5][qq] + dpart[6][qq];
        float xo = Xcur[(size_t)d * NPT + q0 + qq];
        float xn = ETA * num / dn + (1.0f - ETA) * xo;
        Xnext[(size_t)d * NPT + q0 + qq] = xn;
        cols_out[(size_t)d * NPT + q0 + inv] = (bf16_t)xn;
        txn[qq][d] = xn;
    }
    __syncthreads();

    // Phase C (q-major: rows_out coalesced).
#pragma unroll
    for (int e = 0; e < 2; ++e) {
        int idx = tid + e * 512;
        int qq = idx >> 5, d = idx & 31;
        rows_out[(size_t)(q0 + qq) * DIM + d] = (bf16_t)txn[qq][d];
    }
}

extern "C" void kernel_launch(void* const* d_in, const int* in_sizes, int n_in,
                              void* d_out, int out_size, void* d_ws, size_t ws_size,
                              hipStream_t stream) {
    const float* x_in = (const float*)d_in[0];
    float* out = (float*)d_out;

    const size_t DN = (size_t)DIM * NPT;
    // Workspace: 4 bf16 pack buffers (ping-pong), fp32 partials.
    bf16_t* rows0 = (bf16_t*)d_ws;
    bf16_t* cols0 = rows0 + DN;
    bf16_t* rows1 = cols0 + DN;
    bf16_t* cols1 = rows1 + DN;
    float* part_num = (float*)(cols1 + DN);                 // KSEG * NPT * DIM f32
    float* part_den = part_num + (size_t)KSEG * NPT * DIM;  // KSEG * NPT f32

    pack_kernel<<<NPT / 32, 256, 0, stream>>>(x_in, rows0, cols0, out);

    for (int it = 0; it < NITER; ++it) {
        const float* Xcur = (it == 0) ? x_in : out + (size_t)it * DN;
        bf16_t* rin  = (it & 1) ? rows1 : rows0;
        bf16_t* cin  = (it & 1) ? cols1 : cols0;
        bf16_t* rout = (it & 1) ? rows0 : rows1;
        bf16_t* cout = (it & 1) ? cols0 : cols1;
        msattn_kernel<<<dim3(NQB, KSEG), 512, 0, stream>>>(Xcur, rin, cin,
                                                           part_num, part_den);
        reduce_kernel<<<NPT / 32, 512, 0, stream>>>(part_num, part_den, Xcur,
                                                    out + (size_t)(it + 1) * DN,
                                                    rout, cout);
    }
}